// Round 6
// baseline (178.591 us; speedup 1.0000x reference)
//
#include <hip/hip_runtime.h>
#include <stdint.h>

typedef __bf16 bf16x8 __attribute__((ext_vector_type(8)));
typedef short  short4v __attribute__((ext_vector_type(4)));   // 4 x bf16 bits
typedef float  floatx4 __attribute__((ext_vector_type(4)));
typedef uint32_t u32x4 __attribute__((ext_vector_type(4)));

#define DI __device__ __forceinline__

DI uint16_t f2bf(float f) {
    union { float f; uint32_t i; } v; v.f = f;
    uint32_t u = v.i;
    return (uint16_t)((u + 0x7FFFu + ((u >> 16) & 1u)) >> 16);  // RNE
}
// pack two floats to packed bf16 pair (a -> low half)
DI uint32_t packbf2(float a, float b) {
    return __builtin_amdgcn_perm(__float_as_uint(b) + 0x8000u,
                                 __float_as_uint(a) + 0x8000u, 0x07060302u);
}

// ---------------------------------------------------------------------------
// Kernel 1: projections (fp32 inputs, validated r2-r5).
//   th [blk][4096][32] bf16 (theta, pre-scaled by log2 e)
//   phT[blk][4096][32] bf16 (phi)
//   vP [blk][tile][o=32][k=64] bf16 (g, tile-blocked)
// ---------------------------------------------------------------------------
__global__ __launch_bounds__(256) void proj_kernel(
    const float* __restrict__ x,
    const float* __restrict__ tw, const float* __restrict__ tb,
    const float* __restrict__ pw, const float* __restrict__ pb,
    const float* __restrict__ gw, const float* __restrict__ gb,
    uint16_t* __restrict__ th, uint16_t* __restrict__ phT,
    uint16_t* __restrict__ vP)
{
    int nt = blockIdx.x & 63, blk = blockIdx.x >> 6;
    int tid = threadIdx.x;

    __shared__ float xs[64 * 64];
    int b = blk & 1, q = blk >> 1, qh = q >> 1, qw = q & 1;
    int jn = tid & 63;
    int c0 = tid >> 6;
    int n = nt * 64 + jn;
    const float* xg = x + (size_t)b * 1048576 +
                      (size_t)(qh * 64 + nt) * 128 + qw * 64 + jn;
    for (int cc = c0; cc < 64; cc += 4)
        xs[cc * 64 + jn] = xg[(size_t)cc * 16384];
    __syncthreads();

    int o0 = (tid >> 6) * 8;
    float at[8], ap[8], ag[8];
#pragma unroll
    for (int k = 0; k < 8; k++) { at[k] = tb[o0+k]; ap[k] = pb[o0+k]; ag[k] = gb[o0+k]; }
    for (int c = 0; c < 64; ++c) {
        float xv = xs[c * 64 + jn];
#pragma unroll
        for (int k = 0; k < 8; k++) {
            at[k] += tw[(o0+k)*64 + c] * xv;
            ap[k] += pw[(o0+k)*64 + c] * xv;
            ag[k] += gw[(o0+k)*64 + c] * xv;
        }
    }
#pragma unroll
    for (int k = 0; k < 8; k++) at[k] *= 1.44269504088896f;   // log2(e)

    uint16_t* dT = th  + ((size_t)blk * 4096 + n) * 32 + o0;
    uint16_t* dP = phT + ((size_t)blk * 4096 + n) * 32 + o0;
#pragma unroll
    for (int k = 0; k < 8; k += 2) {
        *(uint32_t*)(dT + k) = (uint32_t)f2bf(at[k]) | ((uint32_t)f2bf(at[k+1]) << 16);
        *(uint32_t*)(dP + k) = (uint32_t)f2bf(ap[k]) | ((uint32_t)f2bf(ap[k+1]) << 16);
    }
    uint16_t* dV = vP + (size_t)blk * 131072 + (size_t)nt * 2048 + o0 * 64 + jn;
#pragma unroll
    for (int k = 0; k < 8; k++) dV[k * 64] = f2bf(ag[k]);
}

// ---------------------------------------------------------------------------
// Kernel 2: fused attention + W-projection + BN partial sums.
// Transposed-P formulation (validated r3-r5). 128-key tiles (32 iters):
// halves barriers, doubles the prefetch->use window (~500 cyc) to cover L2
// latency. Inner subtile is phase-batched for ILP: 12 LDS reads -> 4 S-MFMA
// -> 16 exp2 + 8 perm -> 12 PV-MFMA. Epilogue unchanged from r5.
// grid: blk(8) x rg(64) = 512 WGs of 4 waves.
// ---------------------------------------------------------------------------
__global__ __launch_bounds__(256, 2) void flash_kernel(
    const uint16_t* __restrict__ th, const uint16_t* __restrict__ phT,
    const uint16_t* __restrict__ vP, const float* __restrict__ w_w,
    const float* __restrict__ w_b, float* __restrict__ wy,
    float2* __restrict__ partials)
{
    __shared__ uint16_t ldsK[2][2][64 * 40];   // [buf][subtile][64 keys x 40 ch]
    __shared__ uint16_t ldsV[2][2][32 * 72];   // [buf][subtile][32 o x 72 keys]
    __shared__ float sred[4][64][2];
    int rg  = blockIdx.x & 63;
    int blk = blockIdx.x >> 6;
    int tid = threadIdx.x, wid = tid >> 6, lane = tid & 63;
    int quad = lane >> 4, low = lane & 15;
    int n0 = rg * 64 + wid * 16;

    const uint16_t* thB = th  + (size_t)blk * 131072;
    const uint16_t* kG  = phT + (size_t)blk * 131072;
    const uint16_t* vG  = vP  + (size_t)blk * 131072;

    bf16x8 qf = *(const bf16x8*)(thB + (n0 + low) * 32 + quad * 8);

    const int kWr = (tid >> 2) * 40 + (tid & 3) * 8;   // u16 idx, 16B aligned
    const int vWr = (tid >> 3) * 72 + (tid & 7) * 8;
    const u32x4* kSrc = (const u32x4*)kG + tid;        // subtile s: +s*256
    const u32x4* vSrc = (const u32x4*)vG + tid;

    u32x4 kr0 = kSrc[0],  kr1 = kSrc[256];
    u32x4 vr0 = vSrc[0],  vr1 = vSrc[256];
    *(u32x4*)(&ldsK[0][0][kWr]) = kr0;  *(u32x4*)(&ldsK[0][1][kWr]) = kr1;
    *(u32x4*)(&ldsV[0][0][vWr]) = vr0;  *(u32x4*)(&ldsV[0][1][vWr]) = vr1;
    __syncthreads();

    floatx4 zero = {0.f, 0.f, 0.f, 0.f};
    floatx4 oa0 = zero, oa1 = zero, os = zero;
    union { uint32_t u[2]; short4v v; } ones;
    ones.u[0] = 0x3F803F80u; ones.u[1] = 0x3F803F80u;

    for (int t = 0; t < 32; ++t) {
        int buf = t & 1;
        if (t < 31) {
            kr0 = kSrc[(2*t + 2) * 256]; kr1 = kSrc[(2*t + 3) * 256];
            vr0 = vSrc[(2*t + 2) * 256]; vr1 = vSrc[(2*t + 3) * 256];
        }
#pragma unroll
        for (int s = 0; s < 2; ++s) {
            const uint16_t* Kb = ldsK[buf][s];
            const uint16_t* Vb = ldsV[buf][s];
            bf16x8  kf[4]; short4v va[4], vb[4];
#pragma unroll
            for (int c = 0; c < 4; ++c) {
                kf[c] = *(const bf16x8*)(Kb + (c * 16 + low) * 40 + quad * 8);
                va[c] = *(const short4v*)(Vb + low * 72 + c * 16 + quad * 4);
                vb[c] = *(const short4v*)(Vb + (16 + low) * 72 + c * 16 + quad * 4);
            }
            floatx4 sa[4];
#pragma unroll
            for (int c = 0; c < 4; ++c)
                sa[c] = __builtin_amdgcn_mfma_f32_16x16x32_bf16(kf[c], qf, zero, 0, 0, 0);
            union { uint32_t u[2]; short4v v; } P[4];
#pragma unroll
            for (int c = 0; c < 4; ++c) {
                float p0 = __builtin_amdgcn_exp2f(sa[c][0]);
                float p1 = __builtin_amdgcn_exp2f(sa[c][1]);
                float p2 = __builtin_amdgcn_exp2f(sa[c][2]);
                float p3 = __builtin_amdgcn_exp2f(sa[c][3]);
                P[c].u[0] = packbf2(p0, p1);
                P[c].u[1] = packbf2(p2, p3);
            }
#pragma unroll
            for (int c = 0; c < 4; ++c) {
                oa0 = __builtin_amdgcn_mfma_f32_16x16x16bf16_1k(va[c], P[c].v, oa0, 0, 0, 0);
                oa1 = __builtin_amdgcn_mfma_f32_16x16x16bf16_1k(vb[c], P[c].v, oa1, 0, 0, 0);
                os  = __builtin_amdgcn_mfma_f32_16x16x16bf16_1k(ones.v, P[c].v, os, 0, 0, 0);
            }
        }
        if (t < 31) {
            *(u32x4*)(&ldsK[buf ^ 1][0][kWr]) = kr0;
            *(u32x4*)(&ldsK[buf ^ 1][1][kWr]) = kr1;
            *(u32x4*)(&ldsV[buf ^ 1][0][vWr]) = vr0;
            *(u32x4*)(&ldsV[buf ^ 1][1][vWr]) = vr1;
        }
        __syncthreads();
    }

    // ---- epilogue: normalize, W-projection via MFMA, BN partials ----
    float rinv = 1.0f / os[0];
    union { uint32_t u[2]; short4v v; } Y0, Y1;
    Y0.u[0] = packbf2(oa0[0] * rinv, oa0[1] * rinv);
    Y0.u[1] = packbf2(oa0[2] * rinv, oa0[3] * rinv);
    Y1.u[0] = packbf2(oa1[0] * rinv, oa1[1] * rinv);
    Y1.u[1] = packbf2(oa1[2] * rinv, oa1[3] * rinv);

    float* wyB = wy + (size_t)blk * 262144;
    int n = n0 + low;
#pragma unroll
    for (int ct = 0; ct < 4; ++ct) {
        floatx4 acc;
#pragma unroll
        for (int r = 0; r < 4; ++r) acc[r] = w_b[ct * 16 + quad * 4 + r];
        floatx4 w0 = *(const floatx4*)(w_w + (ct * 16 + low) * 32 + quad * 4);
        floatx4 w1 = *(const floatx4*)(w_w + (ct * 16 + low) * 32 + 16 + quad * 4);
        union { uint32_t u[2]; short4v v; } W0, W1;
        W0.u[0] = packbf2(w0[0], w0[1]); W0.u[1] = packbf2(w0[2], w0[3]);
        W1.u[0] = packbf2(w1[0], w1[1]); W1.u[1] = packbf2(w1[2], w1[3]);
        acc = __builtin_amdgcn_mfma_f32_16x16x16bf16_1k(W0.v, Y0.v, acc, 0, 0, 0);
        acc = __builtin_amdgcn_mfma_f32_16x16x16bf16_1k(W1.v, Y1.v, acc, 0, 0, 0);
#pragma unroll
        for (int r = 0; r < 4; ++r) {
            wyB[(size_t)(ct * 16 + quad * 4 + r) * 4096 + n] = acc[r];
            float s = acc[r], ss = acc[r] * acc[r];
            s += __shfl_xor(s, 1); ss += __shfl_xor(ss, 1);
            s += __shfl_xor(s, 2); ss += __shfl_xor(ss, 2);
            s += __shfl_xor(s, 4); ss += __shfl_xor(ss, 4);
            s += __shfl_xor(s, 8); ss += __shfl_xor(ss, 8);
            if (low == 0) {
                sred[wid][ct * 16 + quad * 4 + r][0] = s;
                sred[wid][ct * 16 + quad * 4 + r][1] = ss;
            }
        }
    }
    __syncthreads();
    if (tid < 64) {
        float s  = sred[0][tid][0] + sred[1][tid][0] + sred[2][tid][0] + sred[3][tid][0];
        float ss = sred[0][tid][1] + sred[1][tid][1] + sred[2][tid][1] + sred[3][tid][1];
        partials[(size_t)blockIdx.x * 64 + tid] = make_float2(s, ss);
    }
}

// ---------------------------------------------------------------------------
// Kernel 3: BN stats — grid 4 (q), block 256 (=4 groups x 64 c).
// Each thread sums 32 of the 128 WG-partials, LDS reduce across groups.
// ---------------------------------------------------------------------------
__global__ __launch_bounds__(256) void stats_kernel(
    const float2* __restrict__ partials, const float* __restrict__ gamma,
    const float* __restrict__ beta, float2* __restrict__ stats)
{
    int q = blockIdx.x;
    int c = threadIdx.x & 63, g = threadIdx.x >> 6;
    float S = 0.f, SS = 0.f;
    for (int w = g; w < 128; w += 4) {         // b(2) x rg(64)
        int wg = (q * 2 + (w >> 6)) * 64 + (w & 63);
        float2 p = partials[(size_t)wg * 64 + c];
        S += p.x; SS += p.y;
    }
    __shared__ float sh[2][4][64];
    sh[0][g][c] = S; sh[1][g][c] = SS;
    __syncthreads();
    if (threadIdx.x < 64) {
        int cc = threadIdx.x;
        float St  = sh[0][0][cc] + sh[0][1][cc] + sh[0][2][cc] + sh[0][3][cc];
        float SSt = sh[1][0][cc] + sh[1][1][cc] + sh[1][2][cc] + sh[1][3][cc];
        float mu  = St * (1.0f / 8192.0f);
        float var = SSt * (1.0f / 8192.0f) - mu * mu;
        float scale = gamma[cc] * rsqrtf(var + 1e-5f);
        float shift = beta[cc] - mu * scale;
        stats[q * 64 + cc] = make_float2(scale, shift);
    }
}

// ---------------------------------------------------------------------------
// Kernel 4: out = (wy * scale + shift) + x, float4-vectorized reassembly.
// ---------------------------------------------------------------------------
__global__ __launch_bounds__(256) void final_kernel(
    const float* __restrict__ wy, const float2* __restrict__ stats,
    const float* __restrict__ x, float* __restrict__ out)
{
    size_t base = ((size_t)blockIdx.x * 256 + threadIdx.x) * 4;
    int n   = (int)(base & 4095);
    int c   = (int)((base >> 12) & 63);
    int blk = (int)(base >> 18);
    int b = blk & 1, q = blk >> 1, qh = q >> 1, qw = q & 1;
    int i = n >> 6, j = n & 63;
    float2 sc = stats[q * 64 + c];
    floatx4 wv = *(const floatx4*)(wy + base);
    size_t xa = ((size_t)(b * 64 + c) * 128 + (qh * 64 + i)) * 128 + qw * 64 + j;
    floatx4 xv = *(const floatx4*)(x + xa);
    floatx4 ov;
#pragma unroll
    for (int k = 0; k < 4; ++k) ov[k] = wv[k] * sc.x + sc.y + xv[k];
    *(floatx4*)(out + xa) = ov;
}

// ---------------------------------------------------------------------------
extern "C" void kernel_launch(void* const* d_in, const int* in_sizes, int n_in,
                              void* d_out, int out_size, void* d_ws, size_t ws_size,
                              hipStream_t stream)
{
    const float* x       = (const float*)d_in[0];
    const float* g_w     = (const float*)d_in[1];
    const float* g_b     = (const float*)d_in[2];
    const float* theta_w = (const float*)d_in[3];
    const float* theta_b = (const float*)d_in[4];
    const float* phi_w   = (const float*)d_in[5];
    const float* phi_b   = (const float*)d_in[6];
    const float* w_w     = (const float*)d_in[7];
    const float* w_b     = (const float*)d_in[8];
    const float* gamma   = (const float*)d_in[9];
    const float* beta    = (const float*)d_in[10];

    char* ws = (char*)d_ws;
    uint16_t* th       = (uint16_t*)(ws);                 // 0 .. 2M
    uint16_t* phT      = (uint16_t*)(ws + (2u << 20));    // 2 .. 4M
    uint16_t* vP       = (uint16_t*)(ws + (4u << 20));    // 4 .. 6M
    float*    wy       = (float*)(ws + (6u << 20));       // 6 .. 14M
    float2*   partials = (float2*)(ws + (14u << 20));     // 256 KB
    float2*   stats    = (float2*)(ws + (14u << 20) + (1u << 18));

    proj_kernel  <<<512,  256, 0, stream>>>(x, theta_w, theta_b, phi_w, phi_b,
                                            g_w, g_b, th, phT, vP);
    flash_kernel <<<512,  256, 0, stream>>>(th, phT, vP, w_w, w_b, wy, partials);
    stats_kernel <<<4,    256, 0, stream>>>(partials, gamma, beta, stats);
    final_kernel <<<2048, 256, 0, stream>>>(wy, stats, x, (float*)d_out);
}

// Round 7
// 138.297 us; speedup vs baseline: 1.2914x; 1.2914x over previous
//
#include <hip/hip_runtime.h>
#include <stdint.h>

typedef __bf16 bf16x8 __attribute__((ext_vector_type(8)));
typedef short  short4v __attribute__((ext_vector_type(4)));   // 4 x bf16 bits
typedef float  floatx4 __attribute__((ext_vector_type(4)));
typedef uint32_t u32x4 __attribute__((ext_vector_type(4)));

#define DI __device__ __forceinline__

DI uint16_t f2bf(float f) {
    union { float f; uint32_t i; } v; v.f = f;
    uint32_t u = v.i;
    return (uint16_t)((u + 0x7FFFu + ((u >> 16) & 1u)) >> 16);  // RNE
}
// pack two floats to packed bf16 pair (a -> low half)
DI uint32_t packbf2(float a, float b) {
    return __builtin_amdgcn_perm(__float_as_uint(b) + 0x8000u,
                                 __float_as_uint(a) + 0x8000u, 0x07060302u);
}

// ---------------------------------------------------------------------------
// Kernel 1: projections via MFMA (r6 version was load-issue-bound: 1536
// same-address dword loads/thread, VALUBusy 13%, 50us).
// Per WG: one 64-pixel tile; [96x64]x[64x64] GEMM as 16x16x32 MFMAs.
// A = x (direct global loads, 64B-segment coalesced), B = weight rows
// (32B contiguous, L2-hot). Bias in C operand. g-output transposed via LDS.
//   th [blk][4096][32] bf16 (theta, pre-scaled by log2 e)
//   phT[blk][4096][32] bf16 (phi)
//   vP [blk][tile][o=32][k=64] bf16 (g, tile-blocked)
// grid: 8 blk x 64 nt = 512 WGs of 4 waves; wave owns 16 pixels.
// ---------------------------------------------------------------------------
__global__ __launch_bounds__(256) void proj_kernel(
    const float* __restrict__ x,
    const float* __restrict__ tw, const float* __restrict__ tb,
    const float* __restrict__ pw, const float* __restrict__ pb,
    const float* __restrict__ gw, const float* __restrict__ gb,
    uint16_t* __restrict__ th, uint16_t* __restrict__ phT,
    uint16_t* __restrict__ vP)
{
    __shared__ uint16_t ldsg[32 * 68];     // g-output bounce, pad 68 (8B-align ok)
    int nt = blockIdx.x & 63, blk = blockIdx.x >> 6;
    int tid = threadIdx.x, wid = tid >> 6, lane = tid & 63;
    int quad = lane >> 4, low = lane & 15;

    int b = blk & 1, q = blk >> 1, qh = q >> 1, qw = q & 1;
    int pixA = wid * 16 + low;             // pixel within 64-tile (A-row m=low)
    const float* xg = x + (size_t)b * 1048576 +
                      (size_t)(qh * 64 + nt) * 128 + qw * 64 + pixA;

    // A-frags: A0 = ch 0..31, A1 = ch 32..63;  A[m=low][k=quad*8+j]
    float a0[8], a1[8];
#pragma unroll
    for (int j = 0; j < 8; ++j) {
        a0[j] = xg[(size_t)(quad * 8 + j) * 16384];
        a1[j] = xg[(size_t)(32 + quad * 8 + j) * 16384];
    }
    union { uint32_t u[4]; bf16x8 v; } A0, A1;
#pragma unroll
    for (int j = 0; j < 4; ++j) {
        A0.u[j] = packbf2(a0[2*j], a0[2*j+1]);
        A1.u[j] = packbf2(a1[2*j], a1[2*j+1]);
    }

    // one 16-o output tile: D[m=pixel][n=o0+low] = sum_c x*w + bias
    auto dotile = [&](const float* W, const float* Bv, int o0) -> floatx4 {
        floatx4 acc;
        float bias = Bv[o0 + low];
#pragma unroll
        for (int r = 0; r < 4; ++r) acc[r] = bias;
        const float* wr = W + (o0 + low) * 64 + quad * 8;   // 32B-aligned
        floatx4 w0a = *(const floatx4*)(wr);
        floatx4 w0b = *(const floatx4*)(wr + 4);
        floatx4 w1a = *(const floatx4*)(wr + 32);
        floatx4 w1b = *(const floatx4*)(wr + 36);
        union { uint32_t u[4]; bf16x8 v; } B0, B1;
        B0.u[0] = packbf2(w0a[0], w0a[1]); B0.u[1] = packbf2(w0a[2], w0a[3]);
        B0.u[2] = packbf2(w0b[0], w0b[1]); B0.u[3] = packbf2(w0b[2], w0b[3]);
        B1.u[0] = packbf2(w1a[0], w1a[1]); B1.u[1] = packbf2(w1a[2], w1a[3]);
        B1.u[2] = packbf2(w1b[0], w1b[1]); B1.u[3] = packbf2(w1b[2], w1b[3]);
        acc = __builtin_amdgcn_mfma_f32_16x16x32_bf16(A0.v, B0.v, acc, 0, 0, 0);
        acc = __builtin_amdgcn_mfma_f32_16x16x32_bf16(A1.v, B1.v, acc, 0, 0, 0);
        return acc;
    };

    // D rows: pixel = nt*64 + wid*16 + quad*4 + r; cols: o = o0 + low
    size_t thbase = ((size_t)blk * 4096 + nt * 64 + wid * 16 + quad * 4) * 32;

    floatx4 t0 = dotile(tw, tb, 0), t1 = dotile(tw, tb, 16);
#pragma unroll
    for (int r = 0; r < 4; ++r) {
        th[thbase + r * 32 + low]      = f2bf(t0[r] * 1.44269504088896f);
        th[thbase + r * 32 + 16 + low] = f2bf(t1[r] * 1.44269504088896f);
    }
    floatx4 p0 = dotile(pw, pb, 0), p1 = dotile(pw, pb, 16);
#pragma unroll
    for (int r = 0; r < 4; ++r) {
        phT[thbase + r * 32 + low]      = f2bf(p0[r]);
        phT[thbase + r * 32 + 16 + low] = f2bf(p1[r]);
    }
    floatx4 g0 = dotile(gw, gb, 0), g1 = dotile(gw, gb, 16);
#pragma unroll
    for (int r = 0; r < 4; ++r) {
        ldsg[(low)      * 68 + wid * 16 + quad * 4 + r] = f2bf(g0[r]);
        ldsg[(16 + low) * 68 + wid * 16 + quad * 4 + r] = f2bf(g1[r]);
    }
    __syncthreads();
    // coalesced write-out: thread -> 16B of vP [o=tid>>3][k=(tid&7)*8]
    {
        int o = tid >> 3, k = (tid & 7) * 8;
        const uint16_t* src = &ldsg[o * 68 + k];
        uint64_t lo = *(const uint64_t*)(src);       // 8B-aligned
        uint64_t hi = *(const uint64_t*)(src + 4);
        union { uint64_t q[2]; u32x4 v; } out;
        out.q[0] = lo; out.q[1] = hi;
        *(u32x4*)(vP + (size_t)blk * 131072 + nt * 2048 + tid * 8) = out.v;
    }
}

// ---------------------------------------------------------------------------
// Kernel 2: fused attention + W-projection + BN partial sums (r6 structure:
// 128-key tiles, double-buffered LDS, phase-batched inner loop).
// grid: blk(8) x rg(64) = 512 WGs of 4 waves.
// ---------------------------------------------------------------------------
__global__ __launch_bounds__(256, 2) void flash_kernel(
    const uint16_t* __restrict__ th, const uint16_t* __restrict__ phT,
    const uint16_t* __restrict__ vP, const float* __restrict__ w_w,
    const float* __restrict__ w_b, float* __restrict__ wy,
    float2* __restrict__ partials)
{
    __shared__ uint16_t ldsK[2][2][64 * 40];   // [buf][subtile][64 keys x 40 ch]
    __shared__ uint16_t ldsV[2][2][32 * 72];   // [buf][subtile][32 o x 72 keys]
    __shared__ float sred[4][64][2];
    int rg  = blockIdx.x & 63;
    int blk = blockIdx.x >> 6;
    int tid = threadIdx.x, wid = tid >> 6, lane = tid & 63;
    int quad = lane >> 4, low = lane & 15;
    int n0 = rg * 64 + wid * 16;

    const uint16_t* thB = th  + (size_t)blk * 131072;
    const uint16_t* kG  = phT + (size_t)blk * 131072;
    const uint16_t* vG  = vP  + (size_t)blk * 131072;

    bf16x8 qf = *(const bf16x8*)(thB + (n0 + low) * 32 + quad * 8);

    const int kWr = (tid >> 2) * 40 + (tid & 3) * 8;   // u16 idx, 16B aligned
    const int vWr = (tid >> 3) * 72 + (tid & 7) * 8;
    const u32x4* kSrc = (const u32x4*)kG + tid;        // subtile s: +s*256
    const u32x4* vSrc = (const u32x4*)vG + tid;

    u32x4 kr0 = kSrc[0],  kr1 = kSrc[256];
    u32x4 vr0 = vSrc[0],  vr1 = vSrc[256];
    *(u32x4*)(&ldsK[0][0][kWr]) = kr0;  *(u32x4*)(&ldsK[0][1][kWr]) = kr1;
    *(u32x4*)(&ldsV[0][0][vWr]) = vr0;  *(u32x4*)(&ldsV[0][1][vWr]) = vr1;
    __syncthreads();

    floatx4 zero = {0.f, 0.f, 0.f, 0.f};
    floatx4 oa0 = zero, oa1 = zero, os = zero;
    union { uint32_t u[2]; short4v v; } ones;
    ones.u[0] = 0x3F803F80u; ones.u[1] = 0x3F803F80u;

    for (int t = 0; t < 32; ++t) {
        int buf = t & 1;
        if (t < 31) {
            kr0 = kSrc[(2*t + 2) * 256]; kr1 = kSrc[(2*t + 3) * 256];
            vr0 = vSrc[(2*t + 2) * 256]; vr1 = vSrc[(2*t + 3) * 256];
        }
#pragma unroll
        for (int s = 0; s < 2; ++s) {
            const uint16_t* Kb = ldsK[buf][s];
            const uint16_t* Vb = ldsV[buf][s];
            bf16x8  kf[4]; short4v va[4], vb[4];
#pragma unroll
            for (int c = 0; c < 4; ++c) {
                kf[c] = *(const bf16x8*)(Kb + (c * 16 + low) * 40 + quad * 8);
                va[c] = *(const short4v*)(Vb + low * 72 + c * 16 + quad * 4);
                vb[c] = *(const short4v*)(Vb + (16 + low) * 72 + c * 16 + quad * 4);
            }
            floatx4 sa[4];
#pragma unroll
            for (int c = 0; c < 4; ++c)
                sa[c] = __builtin_amdgcn_mfma_f32_16x16x32_bf16(kf[c], qf, zero, 0, 0, 0);
            union { uint32_t u[2]; short4v v; } P[4];
#pragma unroll
            for (int c = 0; c < 4; ++c) {
                float p0 = __builtin_amdgcn_exp2f(sa[c][0]);
                float p1 = __builtin_amdgcn_exp2f(sa[c][1]);
                float p2 = __builtin_amdgcn_exp2f(sa[c][2]);
                float p3 = __builtin_amdgcn_exp2f(sa[c][3]);
                P[c].u[0] = packbf2(p0, p1);
                P[c].u[1] = packbf2(p2, p3);
            }
#pragma unroll
            for (int c = 0; c < 4; ++c) {
                oa0 = __builtin_amdgcn_mfma_f32_16x16x16bf16_1k(va[c], P[c].v, oa0, 0, 0, 0);
                oa1 = __builtin_amdgcn_mfma_f32_16x16x16bf16_1k(vb[c], P[c].v, oa1, 0, 0, 0);
                os  = __builtin_amdgcn_mfma_f32_16x16x16bf16_1k(ones.v, P[c].v, os, 0, 0, 0);
            }
        }
        if (t < 31) {
            *(u32x4*)(&ldsK[buf ^ 1][0][kWr]) = kr0;
            *(u32x4*)(&ldsK[buf ^ 1][1][kWr]) = kr1;
            *(u32x4*)(&ldsV[buf ^ 1][0][vWr]) = vr0;
            *(u32x4*)(&ldsV[buf ^ 1][1][vWr]) = vr1;
        }
        __syncthreads();
    }

    // ---- epilogue: normalize, W-projection via MFMA, BN partials ----
    float rinv = 1.0f / os[0];
    union { uint32_t u[2]; short4v v; } Y0, Y1;
    Y0.u[0] = packbf2(oa0[0] * rinv, oa0[1] * rinv);
    Y0.u[1] = packbf2(oa0[2] * rinv, oa0[3] * rinv);
    Y1.u[0] = packbf2(oa1[0] * rinv, oa1[1] * rinv);
    Y1.u[1] = packbf2(oa1[2] * rinv, oa1[3] * rinv);

    float* wyB = wy + (size_t)blk * 262144;
    int n = n0 + low;
#pragma unroll
    for (int ct = 0; ct < 4; ++ct) {
        floatx4 acc;
#pragma unroll
        for (int r = 0; r < 4; ++r) acc[r] = w_b[ct * 16 + quad * 4 + r];
        floatx4 w0 = *(const floatx4*)(w_w + (ct * 16 + low) * 32 + quad * 4);
        floatx4 w1 = *(const floatx4*)(w_w + (ct * 16 + low) * 32 + 16 + quad * 4);
        union { uint32_t u[2]; short4v v; } W0, W1;
        W0.u[0] = packbf2(w0[0], w0[1]); W0.u[1] = packbf2(w0[2], w0[3]);
        W1.u[0] = packbf2(w1[0], w1[1]); W1.u[1] = packbf2(w1[2], w1[3]);
        acc = __builtin_amdgcn_mfma_f32_16x16x16bf16_1k(W0.v, Y0.v, acc, 0, 0, 0);
        acc = __builtin_amdgcn_mfma_f32_16x16x16bf16_1k(W1.v, Y1.v, acc, 0, 0, 0);
#pragma unroll
        for (int r = 0; r < 4; ++r) {
            wyB[(size_t)(ct * 16 + quad * 4 + r) * 4096 + n] = acc[r];
            float s = acc[r], ss = acc[r] * acc[r];
            s += __shfl_xor(s, 1); ss += __shfl_xor(ss, 1);
            s += __shfl_xor(s, 2); ss += __shfl_xor(ss, 2);
            s += __shfl_xor(s, 4); ss += __shfl_xor(ss, 4);
            s += __shfl_xor(s, 8); ss += __shfl_xor(ss, 8);
            if (low == 0) {
                sred[wid][ct * 16 + quad * 4 + r][0] = s;
                sred[wid][ct * 16 + quad * 4 + r][1] = ss;
            }
        }
    }
    __syncthreads();
    if (tid < 64) {
        float s  = sred[0][tid][0] + sred[1][tid][0] + sred[2][tid][0] + sred[3][tid][0];
        float ss = sred[0][tid][1] + sred[1][tid][1] + sred[2][tid][1] + sred[3][tid][1];
        partials[(size_t)blockIdx.x * 64 + tid] = make_float2(s, ss);
    }
}

// ---------------------------------------------------------------------------
// Kernel 3: BN stats — grid 4 (q), block 256 (=4 groups x 64 c).
// ---------------------------------------------------------------------------
__global__ __launch_bounds__(256) void stats_kernel(
    const float2* __restrict__ partials, const float* __restrict__ gamma,
    const float* __restrict__ beta, float2* __restrict__ stats)
{
    int q = blockIdx.x;
    int c = threadIdx.x & 63, g = threadIdx.x >> 6;
    float S = 0.f, SS = 0.f;
    for (int w = g; w < 128; w += 4) {         // b(2) x rg(64)
        int wg = (q * 2 + (w >> 6)) * 64 + (w & 63);
        float2 p = partials[(size_t)wg * 64 + c];
        S += p.x; SS += p.y;
    }
    __shared__ float sh[2][4][64];
    sh[0][g][c] = S; sh[1][g][c] = SS;
    __syncthreads();
    if (threadIdx.x < 64) {
        int cc = threadIdx.x;
        float St  = sh[0][0][cc] + sh[0][1][cc] + sh[0][2][cc] + sh[0][3][cc];
        float SSt = sh[1][0][cc] + sh[1][1][cc] + sh[1][2][cc] + sh[1][3][cc];
        float mu  = St * (1.0f / 8192.0f);
        float var = SSt * (1.0f / 8192.0f) - mu * mu;
        float scale = gamma[cc] * rsqrtf(var + 1e-5f);
        float shift = beta[cc] - mu * scale;
        stats[q * 64 + cc] = make_float2(scale, shift);
    }
}

// ---------------------------------------------------------------------------
// Kernel 4: out = (wy * scale + shift) + x, float4-vectorized reassembly.
// ---------------------------------------------------------------------------
__global__ __launch_bounds__(256) void final_kernel(
    const float* __restrict__ wy, const float2* __restrict__ stats,
    const float* __restrict__ x, float* __restrict__ out)
{
    size_t base = ((size_t)blockIdx.x * 256 + threadIdx.x) * 4;
    int n   = (int)(base & 4095);
    int c   = (int)((base >> 12) & 63);
    int blk = (int)(base >> 18);
    int b = blk & 1, q = blk >> 1, qh = q >> 1, qw = q & 1;
    int i = n >> 6, j = n & 63;
    float2 sc = stats[q * 64 + c];
    floatx4 wv = *(const floatx4*)(wy + base);
    size_t xa = ((size_t)(b * 64 + c) * 128 + (qh * 64 + i)) * 128 + qw * 64 + j;
    floatx4 xv = *(const floatx4*)(x + xa);
    floatx4 ov;
#pragma unroll
    for (int k = 0; k < 4; ++k) ov[k] = wv[k] * sc.x + sc.y + xv[k];
    *(floatx4*)(out + xa) = ov;
}

// ---------------------------------------------------------------------------
extern "C" void kernel_launch(void* const* d_in, const int* in_sizes, int n_in,
                              void* d_out, int out_size, void* d_ws, size_t ws_size,
                              hipStream_t stream)
{
    const float* x       = (const float*)d_in[0];
    const float* g_w     = (const float*)d_in[1];
    const float* g_b     = (const float*)d_in[2];
    const float* theta_w = (const float*)d_in[3];
    const float* theta_b = (const float*)d_in[4];
    const float* phi_w   = (const float*)d_in[5];
    const float* phi_b   = (const float*)d_in[6];
    const float* w_w     = (const float*)d_in[7];
    const float* w_b     = (const float*)d_in[8];
    const float* gamma   = (const float*)d_in[9];
    const float* beta    = (const float*)d_in[10];

    char* ws = (char*)d_ws;
    uint16_t* th       = (uint16_t*)(ws);                 // 0 .. 2M
    uint16_t* phT      = (uint16_t*)(ws + (2u << 20));    // 2 .. 4M
    uint16_t* vP       = (uint16_t*)(ws + (4u << 20));    // 4 .. 6M
    float*    wy       = (float*)(ws + (6u << 20));       // 6 .. 14M
    float2*   partials = (float2*)(ws + (14u << 20));     // 256 KB
    float2*   stats    = (float2*)(ws + (14u << 20) + (1u << 18));

    proj_kernel  <<<512,  256, 0, stream>>>(x, theta_w, theta_b, phi_w, phi_b,
                                            g_w, g_b, th, phT, vP);
    flash_kernel <<<512,  256, 0, stream>>>(th, phT, vP, w_w, w_b, wy, partials);
    stats_kernel <<<4,    256, 0, stream>>>(partials, gamma, beta, stats);
    final_kernel <<<2048, 256, 0, stream>>>(wy, stats, x, (float*)d_out);
}